// Round 3
// baseline (208.660 us; speedup 1.0000x reference)
//
#include <hip/hip_runtime.h>

// Trilinear feature-grid interpolation, 2 points per thread for 2x
// memory-level parallelism (16 independent 16B gathers in flight).
// grid layout: [R][R][R][3] = [z][y][x][c], R=256, fp32.

typedef float f4 __attribute__((ext_vector_type(4)));
typedef float f2 __attribute__((ext_vector_type(2)));
typedef f4 f4u __attribute__((aligned(8)));
typedef f2 f2u __attribute__((aligned(8)));

__global__ __launch_bounds__(256) void fgrid3d_kernel(
        const float* __restrict__ inp,
        const float* __restrict__ grid,
        float* __restrict__ out,
        int n2) {          // n2 = number of point-PAIRS
    int t = blockIdx.x * blockDim.x + threadIdx.x;
    if (t >= n2) return;

    // 6 coords for points 2t and 2t+1 (24B contiguous, 8B-aligned).
    f4 cv0 = *(const f4u*)(inp + 6 * t);
    f2 cv1 = *(const f2u*)(inp + 6 * t + 4);
    float cx[2] = {cv0.x, cv0.w};
    float cy[2] = {cv0.y, cv1.x};
    float cz[2] = {cv0.z, cv1.y};

    const float* gbase[2];   // even-aligned (zl,yl) segment pointer
    bool  dsel[2];
    float tx[2], ty[2], tz[2];

#pragma unroll
    for (int p = 0; p < 2; ++p) {
        float sx = cx[p] * 255.0f;
        float sy = cy[p] * 255.0f;
        float sz = cz[p] * 255.0f;
        int xl = (int)floorf(sx); xl = xl < 0 ? 0 : (xl > 254 ? 254 : xl);
        int yl = (int)floorf(sy); yl = yl < 0 ? 0 : (yl > 254 ? 254 : yl);
        int zl = (int)floorf(sz); zl = zl < 0 ? 0 : (zl > 254 ? 254 : zl);
        tx[p] = sx - (float)xl;
        ty[p] = sy - (float)yl;
        tz[p] = sz - (float)zl;
        int b00 = (zl * 65536 + yl * 256 + xl) * 3;
        gbase[p] = grid + (b00 & ~1);
        dsel[p]  = (b00 & 1) != 0;
    }

    // 16 independent 16B gathers, all in flight together.
    f4 A0[2], A1[2], B0[2], B1[2], C0[2], C1[2], D0[2], D1[2];
#pragma unroll
    for (int p = 0; p < 2; ++p) {
        const float* g00 = gbase[p];           // (zl,yl)
        const float* g10 = g00 + 196608;       // (zu,yl)
        A0[p] = *(const f4u*)(g00);
        A1[p] = *(const f4u*)(g00 + 4);
        B0[p] = *(const f4u*)(g00 + 768);      // (zl,yu)
        B1[p] = *(const f4u*)(g00 + 772);
        C0[p] = *(const f4u*)(g10);
        C1[p] = *(const f4u*)(g10 + 4);
        D0[p] = *(const f4u*)(g10 + 768);      // (zu,yu)
        D1[p] = *(const f4u*)(g10 + 772);
    }

#define EXTRACT6(lo, hi, s, d)         \
    do {                               \
        s[0] = d ? lo.y : lo.x;        \
        s[1] = d ? lo.z : lo.y;        \
        s[2] = d ? lo.w : lo.z;        \
        s[3] = d ? hi.x : lo.w;        \
        s[4] = d ? hi.y : hi.x;        \
        s[5] = d ? hi.z : hi.y;        \
    } while (0)

    float o[2][3];
#pragma unroll
    for (int p = 0; p < 2; ++p) {
        bool d = dsel[p];
        float s00[6], s01[6], s10[6], s11[6];
        EXTRACT6(A0[p], A1[p], s00, d);
        EXTRACT6(B0[p], B1[p], s01, d);
        EXTRACT6(C0[p], C1[p], s10, d);
        EXTRACT6(D0[p], D1[p], s11, d);
#pragma unroll
        for (int c = 0; c < 3; ++c) {
            float c00 = s00[c] * (1.0f - tx[p]) + s00[c + 3] * tx[p];
            float c01 = s01[c] * (1.0f - tx[p]) + s01[c + 3] * tx[p];
            float c10 = s10[c] * (1.0f - tx[p]) + s10[c + 3] * tx[p];
            float c11 = s11[c] * (1.0f - tx[p]) + s11[c + 3] * tx[p];
            float c0 = c00 * (1.0f - ty[p]) + c01 * ty[p];
            float c1 = c10 * (1.0f - ty[p]) + c11 * ty[p];
            o[p][c] = c0 * (1.0f - tz[p]) + c1 * tz[p];
        }
    }
#undef EXTRACT6

    // 24B contiguous store per thread.
    f4 w0; w0.x = o[0][0]; w0.y = o[0][1]; w0.z = o[0][2]; w0.w = o[1][0];
    f2 w1; w1.x = o[1][1]; w1.y = o[1][2];
    *(f4u*)(out + 6 * t) = w0;
    *(f2u*)(out + 6 * t + 4) = w1;
}

extern "C" void kernel_launch(void* const* d_in, const int* in_sizes, int n_in,
                              void* d_out, int out_size, void* d_ws, size_t ws_size,
                              hipStream_t stream) {
    const float* inp  = (const float*)d_in[0];  // [N][3]
    const float* grid = (const float*)d_in[1];  // [256][256][256][3]
    float* out = (float*)d_out;                 // [N][3]

    int n = in_sizes[0] / 3;     // N = 2^21 (even)
    int n2 = n / 2;
    int threads = 256;
    int blocks = (n2 + threads - 1) / threads;
    fgrid3d_kernel<<<blocks, threads, 0, stream>>>(inp, grid, out, n2);
}

// Round 4
// 202.113 us; speedup vs baseline: 1.0324x; 1.0324x over previous
//
#include <hip/hip_runtime.h>

// Trilinear feature-grid interpolation with spatial binning for L2 reuse.
// grid layout: [R][R][R][3] = [z][y][x][c], R=256, fp32 (192 MB).
//
// Random point order -> every gather line misses L2 -> ~650 MB EA traffic
// at the measured ~3.2 TB/s random-line wall. Fix: bin points by
// (z>>4, y>>4) into 256 bins; points in a bin share a 17x17-row (~222 KB)
// slab of the grid, which fits in one XCD's 4 MB L2. k_gather pins each
// bin to one XCD (blockIdx%8 round-robin dispatch) so lines are fetched
// once instead of ~128x.

#define NBINS   256
#define BPB     36          // gather blocks per bin (8192 avg pts/bin / 256, padded)
#define NEEDED_WS (33554432u + 8192u)

typedef float f4v __attribute__((ext_vector_type(4)));
typedef f4v f4u __attribute__((aligned(8)));

__device__ __forceinline__ void cell_of(float p, int& l, float& t) {
    float s = p * 255.0f;
    int v = (int)floorf(s);
    v = v < 0 ? 0 : (v > 254 ? 254 : v);
    l = v;
    t = s - (float)v;
}

__device__ __forceinline__ int bin_of(const float* __restrict__ inp, int i) {
    float py = inp[3 * i + 1];
    float pz = inp[3 * i + 2];
    int yl, zl; float ty, tz;
    cell_of(py, yl, ty);
    cell_of(pz, zl, tz);
    return ((zl >> 4) << 4) | (yl >> 4);
}

// ---------------- pass 1: histogram ----------------
__global__ __launch_bounds__(256) void k_hist(const float* __restrict__ inp,
                                              unsigned* __restrict__ hist, int n) {
    __shared__ unsigned h[NBINS];
    int t = threadIdx.x;
    h[t] = 0;
    __syncthreads();
    int stride = gridDim.x * 256;
    for (int i = blockIdx.x * 256 + t; i < n; i += stride)
        atomicAdd(&h[bin_of(inp, i)], 1u);
    __syncthreads();
    if (h[t]) atomicAdd(&hist[t], h[t]);
}

// ---------------- pass 2: exclusive scan ----------------
__global__ __launch_bounds__(256) void k_scan(const unsigned* __restrict__ hist,
                                              unsigned* __restrict__ off,
                                              unsigned* __restrict__ cur) {
    __shared__ unsigned s[NBINS];
    int t = threadIdx.x;
    unsigned v = hist[t];
    s[t] = v;
    __syncthreads();
    for (int d = 1; d < NBINS; d <<= 1) {
        unsigned add = (t >= d) ? s[t - d] : 0u;
        __syncthreads();
        if (t >= d) s[t] += add;
        __syncthreads();
    }
    unsigned excl = s[t] - v;
    off[t] = excl;
    cur[t] = excl;
    if (t == NBINS - 1) off[NBINS] = s[NBINS - 1];
}

// ---------------- pass 3: block-aggregated scatter ----------------
__global__ __launch_bounds__(1024) void k_scatter(const float* __restrict__ inp,
                                                  float4* __restrict__ binned,
                                                  unsigned* __restrict__ cur, int n) {
    __shared__ unsigned cnt[NBINS];
    __shared__ unsigned base[NBINS];
    int t = threadIdx.x;
    int stride = gridDim.x * 1024;
    int iters = (n + stride - 1) / stride;
    for (int it = 0; it < iters; ++it) {
        int i = it * stride + blockIdx.x * 1024 + t;
        if (t < NBINS) cnt[t] = 0;
        __syncthreads();
        int b = 0; unsigned r = 0; float px = 0, py = 0, pz = 0;
        bool valid = (i < n);
        if (valid) {
            px = inp[3 * i];
            py = inp[3 * i + 1];
            pz = inp[3 * i + 2];
            int yl, zl; float ty, tz;
            cell_of(py, yl, ty);
            cell_of(pz, zl, tz);
            b = ((zl >> 4) << 4) | (yl >> 4);
            r = atomicAdd(&cnt[b], 1u);
        }
        __syncthreads();
        if (t < NBINS && cnt[t]) base[t] = atomicAdd(&cur[t], cnt[t]);
        __syncthreads();
        if (valid) {
            float4 v;
            v.x = px; v.y = py; v.z = pz; v.w = __uint_as_float((unsigned)i);
            binned[base[b] + r] = v;
        }
        __syncthreads();
    }
}

// ---------------- pass 4: binned gather / trilerp ----------------
__global__ __launch_bounds__(256) void k_gather(const float4* __restrict__ binned,
                                                const float* __restrict__ grid,
                                                const unsigned* __restrict__ off,
                                                float* __restrict__ out) {
    // blockIdx % 8 -> XCD (round-robin dispatch); pin bin k to XCD k%8.
    int xcd = blockIdx.x & 7;
    int q   = blockIdx.x >> 3;
    int m   = q / BPB;
    int s   = q % BPB;
    int k   = (m << 3) | xcd;          // bin, k % 8 == xcd
    unsigned start = off[k], end = off[k + 1];

    for (unsigned p = start + (unsigned)(s * 256 + threadIdx.x); p < end;
         p += (unsigned)(BPB * 256)) {
        float4 v = binned[p];
        int xl, yl, zl; float tx, ty, tz;
        cell_of(v.x, xl, tx);
        cell_of(v.y, yl, ty);
        cell_of(v.z, zl, tz);

        int b00 = (zl * 65536 + yl * 256 + xl) * 3;
        const float* g00 = grid + (b00 & ~1);
        const float* g10 = g00 + 196608;
        bool d = (b00 & 1) != 0;

        f4v A0 = *(const f4u*)(g00);
        f4v A1 = *(const f4u*)(g00 + 4);
        f4v B0 = *(const f4u*)(g00 + 768);
        f4v B1 = *(const f4u*)(g00 + 772);
        f4v C0 = *(const f4u*)(g10);
        f4v C1 = *(const f4u*)(g10 + 4);
        f4v D0 = *(const f4u*)(g10 + 768);
        f4v D1 = *(const f4u*)(g10 + 772);

#define EXTRACT6(lo, hi, sarr)             \
        do {                               \
            sarr[0] = d ? lo.y : lo.x;     \
            sarr[1] = d ? lo.z : lo.y;     \
            sarr[2] = d ? lo.w : lo.z;     \
            sarr[3] = d ? hi.x : lo.w;     \
            sarr[4] = d ? hi.y : hi.x;     \
            sarr[5] = d ? hi.z : hi.y;     \
        } while (0)

        float s00[6], s01[6], s10[6], s11[6];
        EXTRACT6(A0, A1, s00);
        EXTRACT6(B0, B1, s01);
        EXTRACT6(C0, C1, s10);
        EXTRACT6(D0, D1, s11);
#undef EXTRACT6

        unsigned idx = __float_as_uint(v.w);
        float* o = out + 3 * (int)idx;
#pragma unroll
        for (int c = 0; c < 3; ++c) {
            float c00 = s00[c] * (1.0f - tx) + s00[c + 3] * tx;
            float c01 = s01[c] * (1.0f - tx) + s01[c + 3] * tx;
            float c10 = s10[c] * (1.0f - tx) + s10[c + 3] * tx;
            float c11 = s11[c] * (1.0f - tx) + s11[c + 3] * tx;
            float c0 = c00 * (1.0f - ty) + c01 * ty;
            float c1 = c10 * (1.0f - ty) + c11 * ty;
            o[c] = c0 * (1.0f - tz) + c1 * tz;
        }
    }
}

// ---------------- fallback (ws too small): direct version ----------------
__global__ __launch_bounds__(256) void k_direct(const float* __restrict__ inp,
                                                const float* __restrict__ grid,
                                                float* __restrict__ out, int n) {
    int i = blockIdx.x * blockDim.x + threadIdx.x;
    if (i >= n) return;
    int xl, yl, zl; float tx, ty, tz;
    cell_of(inp[3 * i + 0], xl, tx);
    cell_of(inp[3 * i + 1], yl, ty);
    cell_of(inp[3 * i + 2], zl, tz);
    int b00 = (zl * 65536 + yl * 256 + xl) * 3;
    int b01 = b00 + 768, b10 = b00 + 196608, b11 = b10 + 768;
    float s00[6], s01[6], s10[6], s11[6];
#pragma unroll
    for (int kk = 0; kk < 6; ++kk) s00[kk] = grid[b00 + kk];
#pragma unroll
    for (int kk = 0; kk < 6; ++kk) s01[kk] = grid[b01 + kk];
#pragma unroll
    for (int kk = 0; kk < 6; ++kk) s10[kk] = grid[b10 + kk];
#pragma unroll
    for (int kk = 0; kk < 6; ++kk) s11[kk] = grid[b11 + kk];
#pragma unroll
    for (int c = 0; c < 3; ++c) {
        float c00 = s00[c] * (1.0f - tx) + s00[c + 3] * tx;
        float c01 = s01[c] * (1.0f - tx) + s01[c + 3] * tx;
        float c10 = s10[c] * (1.0f - tx) + s10[c + 3] * tx;
        float c11 = s11[c] * (1.0f - tx) + s11[c + 3] * tx;
        float c0 = c00 * (1.0f - ty) + c01 * ty;
        float c1 = c10 * (1.0f - ty) + c11 * ty;
        out[3 * i + c] = c0 * (1.0f - tz) + c1 * tz;
    }
}

extern "C" void kernel_launch(void* const* d_in, const int* in_sizes, int n_in,
                              void* d_out, int out_size, void* d_ws, size_t ws_size,
                              hipStream_t stream) {
    const float* inp  = (const float*)d_in[0];  // [N][3]
    const float* grid = (const float*)d_in[1];  // [256][256][256][3]
    float* out = (float*)d_out;                 // [N][3]
    int n = in_sizes[0] / 3;

    if (ws_size < (size_t)NEEDED_WS) {
        int blocks = (n + 255) / 256;
        k_direct<<<blocks, 256, 0, stream>>>(inp, grid, out, n);
        return;
    }

    char* ws = (char*)d_ws;
    float4*   binned = (float4*)ws;                         // 2M x 16B = 32 MB
    unsigned* off    = (unsigned*)(ws + 33554432);          // [257]
    unsigned* cur    = (unsigned*)(ws + 33554432 + 2048);   // [256]
    unsigned* hist   = (unsigned*)(ws + 33554432 + 4096);   // [256]

    hipMemsetAsync(hist, 0, NBINS * sizeof(unsigned), stream);
    k_hist   <<<1024, 256,  0, stream>>>(inp, hist, n);
    k_scan   <<<1,    256,  0, stream>>>(hist, off, cur);
    k_scatter<<<256,  1024, 0, stream>>>(inp, binned, cur, n);
    k_gather <<<NBINS * BPB, 256, 0, stream>>>(binned, grid, off, out);
}

// Round 5
// 179.251 us; speedup vs baseline: 1.1641x; 1.1275x over previous
//
#include <hip/hip_runtime.h>

// Trilinear feature-grid interpolation, LDS-staged spatial bins.
// grid layout: [R][R][R][3] = [z][y][x][c], R=256, fp32 (192 MB).
//
// Round-4 evidence: after (z,y)-binning, k_gather is bound by the L1/TCP
// divergent-gather path (172 us at only 1.24 TB/s EA, VALUBusy 3.5%).
// Fix: 16^3-cell bins (4096 bins, ~512 pts each). One 512-thread block per
// bin stages the bin's 17x17x17-cell corner slab (~59 KB) into LDS with
// coalesced float4 loads, then serves all 8-corner gathers from LDS.

#define NBINS 4096
#define GBLK  512
#define SROWS 289           // 17*17 (z,y) row-chunks per slab
#define ROWF  52            // padded floats per chunk (51 used = 17 cells x 3)
#define LDSF  (SROWS * ROWF)   // 15028 floats = 60112 B
#define NEEDED_WS (33554432u + 65536u)

typedef float f4v __attribute__((ext_vector_type(4)));
typedef float f2v __attribute__((ext_vector_type(2)));
typedef f4v f4u __attribute__((aligned(8)));
typedef f2v f2u __attribute__((aligned(8)));

__device__ __forceinline__ void cell_of(float p, int& l, float& t) {
    float s = p * 255.0f;
    int v = (int)floorf(s);
    v = v < 0 ? 0 : (v > 254 ? 254 : v);
    l = v;
    t = s - (float)v;
}

__device__ __forceinline__ int bin3(float px, float py, float pz) {
    int xl, yl, zl; float tx, ty, tz;
    cell_of(px, xl, tx);
    cell_of(py, yl, ty);
    cell_of(pz, zl, tz);
    return ((zl >> 4) << 8) | ((yl >> 4) << 4) | (xl >> 4);
}

// ---------------- pass 1: histogram (4096 bins) ----------------
__global__ __launch_bounds__(1024) void k_hist(const float* __restrict__ inp,
                                               unsigned* __restrict__ hist, int n) {
    __shared__ unsigned h[NBINS];
    int t = threadIdx.x;
    for (int i = t; i < NBINS; i += 1024) h[i] = 0;
    __syncthreads();
    int stride = gridDim.x * 1024;
    for (int i = blockIdx.x * 1024 + t; i < n; i += stride)
        atomicAdd(&h[bin3(inp[3 * i], inp[3 * i + 1], inp[3 * i + 2])], 1u);
    __syncthreads();
    for (int i = t; i < NBINS; i += 1024)
        if (h[i]) atomicAdd(&hist[i], h[i]);
}

// ---------------- pass 2: exclusive scan over 4096 ----------------
__global__ __launch_bounds__(1024) void k_scan(const unsigned* __restrict__ hist,
                                               unsigned* __restrict__ off,
                                               unsigned* __restrict__ cur) {
    __shared__ unsigned s[1024];
    int t = threadIdx.x;
    unsigned v0 = hist[4 * t], v1 = hist[4 * t + 1];
    unsigned v2 = hist[4 * t + 2], v3 = hist[4 * t + 3];
    unsigned sum = v0 + v1 + v2 + v3;
    s[t] = sum;
    __syncthreads();
    for (int d = 1; d < 1024; d <<= 1) {
        unsigned add = (t >= d) ? s[t - d] : 0u;
        __syncthreads();
        s[t] += add;
        __syncthreads();
    }
    unsigned excl = s[t] - sum;
    unsigned e0 = excl, e1 = excl + v0, e2 = e1 + v1, e3 = e2 + v2;
    off[4 * t] = e0;     cur[4 * t] = e0;
    off[4 * t + 1] = e1; cur[4 * t + 1] = e1;
    off[4 * t + 2] = e2; cur[4 * t + 2] = e2;
    off[4 * t + 3] = e3; cur[4 * t + 3] = e3;
    if (t == 1023) off[NBINS] = s[1023];
}

// ---------------- pass 3: block-aggregated scatter ----------------
__global__ __launch_bounds__(1024) void k_scatter(const float* __restrict__ inp,
                                                  float4* __restrict__ binned,
                                                  unsigned* __restrict__ cur, int n) {
    __shared__ unsigned cnt[NBINS];
    __shared__ unsigned base[NBINS];
    int t = threadIdx.x;
    int stride = gridDim.x * 1024;
    int iters = (n + stride - 1) / stride;
    for (int it = 0; it < iters; ++it) {
        int i = it * stride + blockIdx.x * 1024 + t;
        for (int k = t; k < NBINS; k += 1024) cnt[k] = 0;
        __syncthreads();
        int b = 0; unsigned r = 0; float px = 0, py = 0, pz = 0;
        bool valid = (i < n);
        if (valid) {
            px = inp[3 * i];
            py = inp[3 * i + 1];
            pz = inp[3 * i + 2];
            b = bin3(px, py, pz);
            r = atomicAdd(&cnt[b], 1u);
        }
        __syncthreads();
        for (int k = t; k < NBINS; k += 1024)
            if (cnt[k]) base[k] = atomicAdd(&cur[k], cnt[k]);
        __syncthreads();
        if (valid) {
            float4 v;
            v.x = px; v.y = py; v.z = pz; v.w = __uint_as_float((unsigned)i);
            binned[base[b] + r] = v;
        }
        __syncthreads();
    }
}

// ---------------- pass 4: LDS-staged gather / trilerp ----------------
__global__ __launch_bounds__(GBLK) void k_gather(const float4* __restrict__ binned,
                                                 const float* __restrict__ grid,
                                                 const unsigned* __restrict__ off,
                                                 float* __restrict__ out) {
    __shared__ float slab[LDSF];
    int bin = blockIdx.x;
    int x0 = (bin & 15) << 4;
    int y0 = ((bin >> 4) & 15) << 4;
    int z0 = (bin >> 8) << 4;
    int t = threadIdx.x;

    // Stage 289 row-chunks of 51 floats (cells x0..x0+16 of rows
    // (z0..z0+16, y0..y0+16)), 13x float4 per chunk (last at float 48).
    for (int u = t; u < SROWS * 13; u += GBLK) {
        int chunk = u / 13;
        int j = u - chunk * 13;
        if (j == 12 && x0 == 240) continue;   // cells >255 never read; avoids OOB
        int o = (j == 12) ? 48 : (j << 2);
        int zc = chunk / 17;
        int yc = chunk - zc * 17;
        int zg = z0 + zc; zg = zg > 255 ? 255 : zg;   // clamped rows unread
        int yg = y0 + yc; yg = yg > 255 ? 255 : yg;
        const float* src = grid + ((zg << 16) | (yg << 8) | x0) * 3 + o;
        *(f4v*)(&slab[chunk * ROWF + o]) = *(const f4u*)src;
    }
    __syncthreads();

    unsigned start = off[bin], end = off[bin + 1];
    for (unsigned p = start + (unsigned)t; p < end; p += (unsigned)GBLK) {
        float4 v = binned[p];
        int xl, yl, zl; float tx, ty, tz;
        cell_of(v.x, xl, tx);
        cell_of(v.y, yl, ty);
        cell_of(v.z, zl, tz);
        int xc = xl - x0, yc = yl - y0, zc = zl - z0;

        int r0 = (zc * 17 + yc) * ROWF + xc * 3;
        int e = r0 & ~1;
        bool d = (r0 & 1) != 0;

#define SEG_READ(b, s)                                   \
        do {                                             \
            f2v q0 = *(const f2u*)(&slab[(b)]);          \
            f2v q1 = *(const f2u*)(&slab[(b) + 2]);      \
            f2v q2 = *(const f2u*)(&slab[(b) + 4]);      \
            f2v q3 = *(const f2u*)(&slab[(b) + 6]);      \
            s[0] = d ? q0.y : q0.x;                      \
            s[1] = d ? q1.x : q0.y;                      \
            s[2] = d ? q1.y : q1.x;                      \
            s[3] = d ? q2.x : q1.y;                      \
            s[4] = d ? q2.y : q2.x;                      \
            s[5] = d ? q3.x : q2.y;                      \
        } while (0)

        float s00[6], s01[6], s10[6], s11[6];
        SEG_READ(e,              s00);   // (zc,   yc)
        SEG_READ(e + ROWF,       s01);   // (zc,   yc+1)
        SEG_READ(e + 17 * ROWF,  s10);   // (zc+1, yc)
        SEG_READ(e + 18 * ROWF,  s11);   // (zc+1, yc+1)
#undef SEG_READ

        unsigned idx = __float_as_uint(v.w);
        float* o = out + 3 * (int)idx;
#pragma unroll
        for (int c = 0; c < 3; ++c) {
            float c00 = s00[c] * (1.0f - tx) + s00[c + 3] * tx;
            float c01 = s01[c] * (1.0f - tx) + s01[c + 3] * tx;
            float c10 = s10[c] * (1.0f - tx) + s10[c + 3] * tx;
            float c11 = s11[c] * (1.0f - tx) + s11[c + 3] * tx;
            float c0 = c00 * (1.0f - ty) + c01 * ty;
            float c1 = c10 * (1.0f - ty) + c11 * ty;
            o[c] = c0 * (1.0f - tz) + c1 * tz;
        }
    }
}

// ---------------- fallback (ws too small): direct version ----------------
__global__ __launch_bounds__(256) void k_direct(const float* __restrict__ inp,
                                                const float* __restrict__ grid,
                                                float* __restrict__ out, int n) {
    int i = blockIdx.x * blockDim.x + threadIdx.x;
    if (i >= n) return;
    int xl, yl, zl; float tx, ty, tz;
    cell_of(inp[3 * i + 0], xl, tx);
    cell_of(inp[3 * i + 1], yl, ty);
    cell_of(inp[3 * i + 2], zl, tz);
    int b00 = (zl * 65536 + yl * 256 + xl) * 3;
    int b01 = b00 + 768, b10 = b00 + 196608, b11 = b10 + 768;
    float s00[6], s01[6], s10[6], s11[6];
#pragma unroll
    for (int kk = 0; kk < 6; ++kk) s00[kk] = grid[b00 + kk];
#pragma unroll
    for (int kk = 0; kk < 6; ++kk) s01[kk] = grid[b01 + kk];
#pragma unroll
    for (int kk = 0; kk < 6; ++kk) s10[kk] = grid[b10 + kk];
#pragma unroll
    for (int kk = 0; kk < 6; ++kk) s11[kk] = grid[b11 + kk];
#pragma unroll
    for (int c = 0; c < 3; ++c) {
        float c00 = s00[c] * (1.0f - tx) + s00[c + 3] * tx;
        float c01 = s01[c] * (1.0f - tx) + s01[c + 3] * tx;
        float c10 = s10[c] * (1.0f - tx) + s10[c + 3] * tx;
        float c11 = s11[c] * (1.0f - tx) + s11[c + 3] * tx;
        float c0 = c00 * (1.0f - ty) + c01 * ty;
        float c1 = c10 * (1.0f - ty) + c11 * ty;
        out[3 * i + c] = c0 * (1.0f - tz) + c1 * tz;
    }
}

extern "C" void kernel_launch(void* const* d_in, const int* in_sizes, int n_in,
                              void* d_out, int out_size, void* d_ws, size_t ws_size,
                              hipStream_t stream) {
    const float* inp  = (const float*)d_in[0];  // [N][3]
    const float* grid = (const float*)d_in[1];  // [256][256][256][3]
    float* out = (float*)d_out;                 // [N][3]
    int n = in_sizes[0] / 3;

    if (ws_size < (size_t)NEEDED_WS) {
        int blocks = (n + 255) / 256;
        k_direct<<<blocks, 256, 0, stream>>>(inp, grid, out, n);
        return;
    }

    char* ws = (char*)d_ws;
    float4*   binned = (float4*)ws;                          // 2M x 16B = 32 MB
    unsigned* off    = (unsigned*)(ws + 33554432);           // [4097]
    unsigned* cur    = (unsigned*)(ws + 33554432 + 16388);   // [4096]
    unsigned* hist   = (unsigned*)(ws + 33554432 + 16388 + 16384); // [4096]

    hipMemsetAsync(hist, 0, NBINS * sizeof(unsigned), stream);
    k_hist   <<<256,   1024, 0, stream>>>(inp, hist, n);
    k_scan   <<<1,     1024, 0, stream>>>(hist, off, cur);
    k_scatter<<<256,   1024, 0, stream>>>(inp, binned, cur, n);
    k_gather <<<NBINS, GBLK, 0, stream>>>(binned, grid, off, out);
}